// Round 1
// baseline (135.331 us; speedup 1.0000x reference)
//
#include <hip/hip_runtime.h>
#include <hip/hip_bf16.h>

#define NN   102      // nodes
#define NE   83       // edges in baked list (pre-filter)
#define NPAD 128      // padded M

using bf16x8 = __attribute__((ext_vector_type(8))) short;   // 8 bf16 (4 VGPRs)
using f32x4  = __attribute__((ext_vector_type(4))) float;   // MFMA C/D

__device__ __constant__ int EDGES_C[NE * 2] = {
    0,6, 0,5, 6,8, 5,7, 0,62, 62,63, 63,64, 59,64, 59,60, 60,61, 61,62,
    0,74, 71,72, 72,73, 73,74, 74,75, 75,76, 76,77, 77,78, 78,79, 79,80,
    80,81, 81,82, 71,82, 71,83, 77,87, 83,84, 84,85, 85,86, 86,87, 87,88,
    88,89, 89,90, 83,90, 0,65, 65,66, 66,67, 67,68, 68,69, 69,70, 65,70,
    7,91, 91,92, 92,93, 93,94, 94,95, 91,96, 96,97, 97,98, 98,99, 91,100,
    100,101, 101,102, 102,103, 91,104, 104,105, 105,106, 106,107, 91,108,
    108,109, 109,110, 110,111, 8,112, 112,113, 113,114, 114,115, 115,116,
    112,117, 117,118, 118,119, 119,120, 112,121, 121,122, 122,123, 123,124,
    112,125, 125,126, 126,127, 127,128, 112,129, 129,130, 130,131, 131,132
};

// ws layout (bytes)
#define WS_BFRAG 0                   // 16 frags * 64 lanes * 16B = 16384
#define WS_OFF   16384               // 103 ints (padded to 512)
#define WS_ER    (16384 + 512)       // up to 256 ints
#define WS_EN    (16384 + 512 + 1024)// up to 256 floats
// total 19456 bytes

__device__ inline unsigned short f2bf(float f) {
  union { float f; unsigned u; } v; v.f = f;
  unsigned r = v.u + 0x7fffu + ((v.u >> 16) & 1u);   // RNE
  return (unsigned short)(r >> 16);
}

// One small block: builds normalized-graph CSR + per-lane bf16 B-fragments of W_proj.
__global__ void gnn_setup(const float* __restrict__ Wp, char* __restrict__ ws) {
  __shared__ float s_dinv[NN];
  __shared__ int   s_cnt[NN];
  __shared__ int   s_off[NN + 1];
  const int t = threadIdx.x;

  if (t < NN) {
    int deg = 1, cnt = 1;                       // self loop
    for (int e = 0; e < NE; ++e) {
      int r = EDGES_C[2*e], c = EDGES_C[2*e+1];
      if (r < NN && c == t) { ++deg; ++cnt; }   // c==t implies c<NN
    }
    s_dinv[t] = 1.0f / sqrtf((float)deg);
    s_cnt[t]  = cnt;
  }
  __syncthreads();
  if (t < NN) {
    int o = 0;
    for (int c = 0; c < t; ++c) o += s_cnt[c];
    s_off[t] = o;
    if (t == NN - 1) s_off[NN] = o + s_cnt[t];
  }
  __syncthreads();
  int*   off = (int*)(ws + WS_OFF);
  int*   er  = (int*)(ws + WS_ER);
  float* en  = (float*)(ws + WS_EN);
  if (t < NN) {
    int c = t, pos = s_off[c];
    float dc = s_dinv[c];
    er[pos] = c; en[pos] = dc * dc; ++pos;      // self loop
    for (int e = 0; e < NE; ++e) {
      int r = EDGES_C[2*e], cc = EDGES_C[2*e+1];
      if (r < NN && cc == c) { er[pos] = r; en[pos] = s_dinv[r] * dc; ++pos; }
    }
    off[c] = s_off[c];
    if (c == 0) off[NN] = s_off[NN];
  }
  // B-fragments: lane holds B[k][col], col = lane&15, k = kc*32 + (lane>>4)*8 + i
  unsigned short* bf = (unsigned short*)(ws + WS_BFRAG);
  for (int idx = t; idx < 16 * 64; idx += blockDim.x) {
    int lane = idx & 63;
    int f    = idx >> 6;          // f = nt*2 + kc
    int nt   = f >> 1, kc = f & 1;
    int e    = nt * 16 + (lane & 15);
    int kb   = kc * 32 + (lane >> 4) * 8;
    unsigned short* dst = bf + idx * 8;
#pragma unroll
    for (int i = 0; i < 8; ++i) dst[i] = f2bf(Wp[(kb + i) * 128 + e]);
  }
}

// One block per batch element; 4 waves; M padded 102->128 (8 M-tiles), N=128 (8 N-tiles), K=64.
__global__ __launch_bounds__(256) void gnn_main(
    const float* __restrict__ x, const float* __restrict__ Wg,
    const float* __restrict__ bg, const float* __restrict__ bp,
    const char* __restrict__ ws, float* __restrict__ out) {
  const int b    = blockIdx.x;
  const int t    = threadIdx.x;
  const int lane = t & 63;
  const int wv   = t >> 6;

  __shared__ float sx[204];
  __shared__ float sy[NPAD][2];
  __shared__ float swg[128];
  __shared__ float sbg[64];
  __shared__ float sbp[128];

  if (t < 204) sx[t] = x[(size_t)b * 204 + t];
  if (t < 128) { swg[t] = Wg[t]; sbp[t] = bp[t]; }
  if (t < 64)  sbg[t] = bg[t];
  __syncthreads();

  // y = S @ xn[b]   (CSR, ~1.5 nnz/row avg)
  if (t < NPAD) {
    float y0 = 0.f, y1 = 0.f;
    if (t < NN) {
      const int*   off = (const int*)(ws + WS_OFF);
      const int*   er  = (const int*)(ws + WS_ER);
      const float* en  = (const float*)(ws + WS_EN);
      int s = off[t], e2 = off[t + 1];
      for (int j = s; j < e2; ++j) {
        int r = er[j]; float w = en[j];
        y0 = fmaf(w, sx[2 * r],     y0);
        y1 = fmaf(w, sx[2 * r + 1], y1);
      }
    }
    sy[t][0] = y0; sy[t][1] = y1;
  }
  __syncthreads();

  // A-fragments in registers: act[row][k] = relu(y0*Wg[0][k] + y1*Wg[1][k] + bg[k])
  const int kb = (lane >> 4) * 8;
  bf16x8 Af[2][2];
#pragma unroll
  for (int m = 0; m < 2; ++m) {
    const int row = (wv * 2 + m) * 16 + (lane & 15);
    const float y0 = sy[row][0], y1 = sy[row][1];
#pragma unroll
    for (int kc = 0; kc < 2; ++kc) {
      bf16x8 a;
#pragma unroll
      for (int i = 0; i < 8; ++i) {
        int h = kc * 32 + kb + i;
        float v = fmaf(y0, swg[h], fmaf(y1, swg[64 + h], sbg[h]));
        v = fmaxf(v, 0.f);
        a[i] = (short)f2bf(v);
      }
      Af[m][kc] = a;
    }
  }

  // B-fragments: 16 coalesced 16B loads (L2-resident, block-invariant)
  const bf16x8* bfr = (const bf16x8*)(ws + WS_BFRAG);
  bf16x8 Bf[8][2];
#pragma unroll
  for (int nt = 0; nt < 8; ++nt) {
    Bf[nt][0] = bfr[(nt * 2 + 0) * 64 + lane];
    Bf[nt][1] = bfr[(nt * 2 + 1) * 64 + lane];
  }
  float bpv[8];
#pragma unroll
  for (int nt = 0; nt < 8; ++nt) bpv[nt] = sbp[nt * 16 + (lane & 15)];

  f32x4 acc[2][8];
#pragma unroll
  for (int m = 0; m < 2; ++m)
#pragma unroll
    for (int nt = 0; nt < 8; ++nt) {
      f32x4 z = {0.f, 0.f, 0.f, 0.f};
      acc[m][nt] = z;
    }

#pragma unroll
  for (int m = 0; m < 2; ++m)
#pragma unroll
    for (int nt = 0; nt < 8; ++nt)
#pragma unroll
      for (int kc = 0; kc < 2; ++kc)
        acc[m][nt] = __builtin_amdgcn_mfma_f32_16x16x32_bf16(
            Af[m][kc], Bf[nt][kc], acc[m][nt], 0, 0, 0);

  // Epilogue: D[row][col], col = lane&15, row = (lane>>4)*4 + j  (m89-verified)
  const int rb = (lane >> 4) * 4;
  const int ec = lane & 15;
#pragma unroll
  for (int m = 0; m < 2; ++m) {
    const int mt = wv * 2 + m;
#pragma unroll
    for (int nt = 0; nt < 8; ++nt) {
#pragma unroll
      for (int j = 0; j < 4; ++j) {
        int row = mt * 16 + rb + j;
        if (row < NN)
          out[((size_t)b * NN + row) * 128 + nt * 16 + ec] = acc[m][nt][j] + bpv[nt];
      }
    }
  }
}

extern "C" void kernel_launch(void* const* d_in, const int* in_sizes, int n_in,
                              void* d_out, int out_size, void* d_ws, size_t ws_size,
                              hipStream_t stream) {
  const float* x  = (const float*)d_in[0];   // (B, 204)
  const float* Wg = (const float*)d_in[1];   // (2, 64)
  const float* bg = (const float*)d_in[2];   // (64,)
  const float* Wp = (const float*)d_in[3];   // (64, 128)
  const float* bp = (const float*)d_in[4];   // (128,)
  float* out = (float*)d_out;                // (B, 102, 128)
  const int B = in_sizes[0] / 204;

  gnn_setup<<<1, 256, 0, stream>>>(Wp, (char*)d_ws);
  gnn_main<<<B, 256, 0, stream>>>(x, Wg, bg, bp, (const char*)d_ws, out);
}